// Round 3
// baseline (347.049 us; speedup 1.0000x reference)
//
#include <hip/hip_runtime.h>
#include <math.h>

#define NN 4096      // nodes
#define CC 512       // concat dim = 8 heads * 64
#define MB (1024*1024)
#define LOG2E 1.4426950408889634f

typedef __attribute__((ext_vector_type(8))) __bf16 bf16x8;
typedef __attribute__((ext_vector_type(4))) float f32x4;
typedef unsigned short ushort_t;
typedef unsigned int uint_t;
typedef unsigned char uchar_t;

#if __has_builtin(__builtin_amdgcn_exp2f)
#define EXP2(x) __builtin_amdgcn_exp2f(x)
#else
#define EXP2(x) exp2f(x)
#endif

static __device__ __forceinline__ float elu1(float x){ return x > 0.f ? x : (__expf(x)-1.f); }
static __device__ __forceinline__ ushort_t f2bf(float f){
    union { float f; uint_t u; } v; v.f = f;
    uint_t r = (v.u + 0x7FFFu + ((v.u >> 16) & 1u)) >> 16;
    return (ushort_t)r;
}

// ---- repack W_att [8][512][64] -> W_all [512][512]  (W_all[k][hd*64+f])
__global__ void k_repack(const float* __restrict__ Watt, float* __restrict__ Wall){
    int idx = blockIdx.x*256 + threadIdx.x;            // < 512*512
    int k = idx >> 9, c = idx & 511;
    Wall[idx] = Watt[(c>>6)*(512*64) + k*64 + (c&63)];
}

// ---- pack adjacency to bits: abits[i][q] = bits of adj[i][q*32 .. +31]
__global__ void k_pack(const int* __restrict__ adj, uint_t* __restrict__ abits){
    int idx = blockIdx.x*256 + threadIdx.x;            // < 4096*128
    int i = idx >> 7, q = idx & 127;
    const int4* p = (const int4*)&adj[(size_t)i*NN + q*32];
    uint_t m = 0;
    #pragma unroll
    for(int g=0; g<8; g++){
        int4 v = p[g];
        m |= (uint_t)(v.x > 0) << (g*4 + 0);
        m |= (uint_t)(v.y > 0) << (g*4 + 1);
        m |= (uint_t)(v.z > 0) << (g*4 + 2);
        m |= (uint_t)(v.w > 0) << (g*4 + 3);
    }
    abits[idx] = m;
}

// ---- generic f32 GEMM: C[M,N]=A[M,K]@B[K,N], row-major. BM=64, BK=16, TM=4.
template<int BN, int TN>
__global__ __launch_bounds__(256) void k_gemm(const float* __restrict__ A,
                                              const float* __restrict__ B,
                                              float* __restrict__ C,
                                              int M, int N, int K){
    constexpr int BM = 64, BK = 16, TM = 4;
    __shared__ float As[BK][BM + 4];
    __shared__ float Bs[BK][BN];
    const int t = threadIdx.x;
    const int i0 = blockIdx.x*BM, j0 = blockIdx.y*BN;
    constexpr int nx = BN / TN;
    const int ty = t / nx, tx = t % nx;
    float acc[TM][TN];
    #pragma unroll
    for(int a=0;a<TM;a++){
        #pragma unroll
        for(int b=0;b<TN;b++) acc[a][b] = 0.f;
    }
    const int ai = t >> 2, ak = (t & 3)*4;
    for(int k0 = 0; k0 < K; k0 += BK){
        __syncthreads();
        float4 av = *(const float4*)&A[(size_t)(i0+ai)*K + k0 + ak];
        As[ak+0][ai]=av.x; As[ak+1][ai]=av.y; As[ak+2][ai]=av.z; As[ak+3][ai]=av.w;
        if constexpr (BN == 64){
            int bk = t >> 4, bj = (t & 15)*4;
            *(float4*)&Bs[bk][bj] = *(const float4*)&B[(size_t)(k0+bk)*N + j0 + bj];
        } else {
            if (t < 128){
                int bk = t >> 3, bj = (t & 7)*4;
                *(float4*)&Bs[bk][bj] = *(const float4*)&B[(size_t)(k0+bk)*N + j0 + bj];
            }
        }
        __syncthreads();
        #pragma unroll
        for(int k=0;k<BK;k++){
            float4 a4 = *(const float4*)&As[k][ty*TM];
            float ar[4] = {a4.x, a4.y, a4.z, a4.w};
            if constexpr (TN == 4){
                float4 b4 = *(const float4*)&Bs[k][tx*4];
                float br[4] = {b4.x, b4.y, b4.z, b4.w};
                #pragma unroll
                for(int a=0;a<TM;a++){
                    #pragma unroll
                    for(int b=0;b<4;b++) acc[a][b] += ar[a]*br[b];
                }
            } else {
                float2 b2 = *(const float2*)&Bs[k][tx*2];
                #pragma unroll
                for(int a=0;a<TM;a++){ acc[a][0] += ar[a]*b2.x; acc[a][1] += ar[a]*b2.y; }
            }
        }
    }
    #pragma unroll
    for(int a=0;a<TM;a++){
        float* cp = &C[(size_t)(i0 + ty*TM + a)*N + j0 + tx*TN];
        if constexpr (TN == 4){
            float4 v = {acc[a][0], acc[a][1], acc[a][2], acc[a][3]};
            *(float4*)cp = v;
        } else {
            float2 v = {acc[a][0], acc[a][1]};
            *(float2*)cp = v;
        }
    }
}

// ---- transpose h_all [4096][512] f32 -> hT [512][4096] bf16 bits
__global__ __launch_bounds__(256) void k_tr(const float* __restrict__ h, ushort_t* __restrict__ hT){
    __shared__ float tile[32][33];
    const int bj = blockIdx.x*32, bc = blockIdx.y*32;
    const int tx = threadIdx.x & 31, ty = threadIdx.x >> 5;   // 32 x 8
    #pragma unroll
    for(int r=0;r<4;r++)
        tile[ty + r*8][tx] = h[(size_t)(bj + ty + r*8)*512 + bc + tx];
    __syncthreads();
    #pragma unroll
    for(int r=0;r<4;r++)
        hT[(size_t)(bc + ty + r*8)*NN + bj + tx] = f2bf(tile[tx][ty + r*8]);
}

// ---- scores layer1 (pre-scaled by log2e)
__global__ void k_scores1(const float* __restrict__ hall, const float* __restrict__ aatt,
                          float* __restrict__ ssrc2, float* __restrict__ sdst2){
    int t = threadIdx.x;
    int hd = t & 7, il = t >> 3;
    int i = blockIdx.x*32 + il;
    const float4* h4 = (const float4*)&hall[(size_t)i*CC + hd*64];
    const float4* a1 = (const float4*)&aatt[hd*128];
    const float4* a2 = (const float4*)&aatt[hd*128 + 64];
    float ss = 0.f, sd = 0.f;
    #pragma unroll
    for(int q=0;q<16;q++){
        float4 h = h4[q], u = a1[q], v = a2[q];
        ss += h.x*u.x + h.y*u.y + h.z*u.z + h.w*u.w;
        sd += h.x*v.x + h.y*v.y + h.z*v.z + h.w*v.w;
    }
    ssrc2[hd*NN + i] = ss*LOG2E;
    sdst2[hd*NN + i] = sd*LOG2E;
}

// ---- attention layer1 via MFMA. grid (256, 4), block 256 = 4 waves.
// wave handles heads {2w,2w+1}; i-tile 16; j-chunk 1024 (32 K-tiles of 32).
// pnumT layout [jc][col 512][i 4096] -> float4 stores.
__global__ __launch_bounds__(256) void k_attn1(
        const ushort_t* __restrict__ hT,
        const float* __restrict__ ssrc2, const float* __restrict__ sdst2,
        const uchar_t* __restrict__ abits,
        float* __restrict__ pnumT, float* __restrict__ pden){
    const int t = threadIdx.x;
    const int l = t & 63;
    const int hd0 = (t >> 6)*2;
    const int i0 = blockIdx.x*16;
    const int jc = blockIdx.y;
    const int lr = l & 15;     // A row / B col / C col
    const int lg = l >> 4;     // k-group (8 j's) / C row-group

    f32x4 acc[2][4] = {};      // [hd][nt]
    f32x4 dacc[2] = {};        // denominators via ones-MFMA

    const float ss[2] = { ssrc2[(hd0+0)*NN + i0 + lr], ssrc2[(hd0+1)*NN + i0 + lr] };
    bf16x8 ones;
    #pragma unroll
    for(int e=0;e<8;e++) ones[e] = (__bf16)1.0f;

    const uchar_t* arow = &abits[(size_t)(i0+lr)*512 + jc*128];

    for(int jt=0; jt<32; ++jt){
        const int jb = jc*1024 + jt*32 + lg*8;
        // loads first (let them fly)
        bf16x8 b[2][4];
        #pragma unroll
        for(int hd=0;hd<2;hd++)
            #pragma unroll
            for(int nt=0;nt<4;nt++)
                b[hd][nt] = *(const bf16x8*)&hT[(size_t)((hd0+hd)*64 + nt*16 + lr)*NN + jb];
        uint_t bits = arow[jt*4 + lg];
        float4 sda[2], sdb[2];
        #pragma unroll
        for(int hd=0;hd<2;hd++){
            sda[hd] = *(const float4*)&sdst2[(hd0+hd)*NN + jb];
            sdb[hd] = *(const float4*)&sdst2[(hd0+hd)*NN + jb + 4];
        }
        // w build (exp2 domain; lrelu = max(s, 0.2s); mask via bit multiply)
        bf16x8 afr[2];
        #pragma unroll
        for(int hd=0;hd<2;hd++){
            float sdv[8] = {sda[hd].x,sda[hd].y,sda[hd].z,sda[hd].w,
                            sdb[hd].x,sdb[hd].y,sdb[hd].z,sdb[hd].w};
            bf16x8 a;
            #pragma unroll
            for(int e=0;e<8;e++){
                float s = ss[hd] + sdv[e];
                float tt = fmaxf(s, 0.2f*s);
                float w = EXP2(tt) * (float)((bits >> e) & 1u);
                a[e] = (__bf16)w;
            }
            afr[hd] = a;
        }
        // MFMA: 8 num + 2 den
        #pragma unroll
        for(int hd=0;hd<2;hd++){
            #pragma unroll
            for(int nt=0;nt<4;nt++)
                acc[hd][nt] = __builtin_amdgcn_mfma_f32_16x16x32_bf16(
                    afr[hd], b[hd][nt], acc[hd][nt], 0, 0, 0);
            dacc[hd] = __builtin_amdgcn_mfma_f32_16x16x32_bf16(
                    afr[hd], ones, dacc[hd], 0, 0, 0);
        }
    }
    // write pnumT: col = hd*64+nt*16+lr, rows i0+lg*4 .. +3 contiguous -> float4
    #pragma unroll
    for(int hd=0;hd<2;hd++)
        #pragma unroll
        for(int nt=0;nt<4;nt++){
            int col = (hd0+hd)*64 + nt*16 + lr;
            float4 v = {acc[hd][nt][0], acc[hd][nt][1], acc[hd][nt][2], acc[hd][nt][3]};
            *(float4*)&pnumT[((size_t)jc*512 + col)*NN + i0 + lg*4] = v;
        }
    if (lr == 0){
        #pragma unroll
        for(int hd=0;hd<2;hd++)
            #pragma unroll
            for(int r=0;r<4;r++)
                pden[((size_t)jc*8 + hd0+hd)*NN + i0 + lg*4 + r] = dacc[hd][r];
    }
}

// ---- reduce layer1: hcatT[c][i] = elu( sum_jc pnumT / sum_jc pden )
__global__ void k_reduce1T(const float* __restrict__ pnumT, const float* __restrict__ pden,
                           float* __restrict__ hcatT){
    int idx = blockIdx.x*256 + threadIdx.x;           // < 512*4096
    int c = idx >> 12, i = idx & 4095, hd = c >> 6;
    float s = 0.f, d = 0.f;
    #pragma unroll
    for(int jc=0;jc<4;jc++){
        s += pnumT[((size_t)jc*512 + c)*NN + i];
        d += pden[((size_t)jc*8 + hd)*NN + i];
    }
    hcatT[(size_t)c*NN + i] = elu1(s/d);
}

// ---- gemm2 from transposed A: C[4096][32] = AT[512][4096]^T @ B[512][32]
__global__ __launch_bounds__(256) void k_gemmAT(const float* __restrict__ AT,
                                                const float* __restrict__ B,
                                                float* __restrict__ C){
    __shared__ float As[32][32];   // [k][i]
    __shared__ float Bs[32][32];   // [k][n]
    const int t = threadIdx.x;
    const int i0 = blockIdx.x*32;
    const int ty = t >> 4, tx = t & 15;
    float acc[2][2] = {{0.f,0.f},{0.f,0.f}};
    for(int k0=0;k0<512;k0+=32){
        __syncthreads();
        { int k = t >> 3, i4 = (t & 7)*4;
          *(float4*)&As[k][i4] = *(const float4*)&AT[(size_t)(k0+k)*NN + i0 + i4]; }
        { int k = t >> 3, n4 = (t & 7)*4;
          *(float4*)&Bs[k][n4] = *(const float4*)&B[(size_t)(k0+k)*32 + n4]; }
        __syncthreads();
        #pragma unroll
        for(int k=0;k<32;k++){
            float2 a2 = *(const float2*)&As[k][ty*2];
            float2 b2 = *(const float2*)&Bs[k][tx*2];
            acc[0][0] += a2.x*b2.x; acc[0][1] += a2.x*b2.y;
            acc[1][0] += a2.y*b2.x; acc[1][1] += a2.y*b2.y;
        }
    }
    #pragma unroll
    for(int a=0;a<2;a++){
        float2 v = {acc[a][0], acc[a][1]};
        *(float2*)&C[(size_t)(i0 + ty*2 + a)*32 + tx*2] = v;
    }
}

// ---- scores layer2 (pre-scaled by log2e)
__global__ void k_scores2(const float* __restrict__ h2, const float* __restrict__ aout,
                          float* __restrict__ ss2, float* __restrict__ sd2){
    int i = blockIdx.x*256 + threadIdx.x;
    const float4* h4 = (const float4*)&h2[(size_t)i*32];
    const float4* a1 = (const float4*)aout;
    const float4* a2 = (const float4*)&aout[32];
    float ss = 0.f, sd = 0.f;
    #pragma unroll
    for(int q=0;q<8;q++){
        float4 h = h4[q], u = a1[q], v = a2[q];
        ss += h.x*u.x + h.y*u.y + h.z*u.z + h.w*u.w;
        sd += h.x*v.x + h.y*v.y + h.z*v.z + h.w*v.w;
    }
    ss2[i] = ss*LOG2E; sd2[i] = sd*LOG2E;
}

// ---- transpose h2 [4096][32] f32 -> h2T [32][4096] bf16
__global__ __launch_bounds__(256) void k_tr2(const float* __restrict__ h2, ushort_t* __restrict__ h2T){
    __shared__ float tile[64][33];
    const int bj = blockIdx.x*64;
    const int t = threadIdx.x;
    const int tx = t & 31, ty = t >> 5;
    #pragma unroll
    for(int r=0;r<8;r++)
        tile[ty + r*8][tx] = h2[(size_t)(bj + ty + r*8)*32 + tx];
    __syncthreads();
    #pragma unroll
    for(int half=0; half<2; half++){
        int c = (t >> 4) + half*16;
        int j4 = (t & 15)*4;
        ushort4 o;
        o.x = f2bf(tile[j4+0][c]); o.y = f2bf(tile[j4+1][c]);
        o.z = f2bf(tile[j4+2][c]); o.w = f2bf(tile[j4+3][c]);
        *(ushort4*)&h2T[(size_t)c*NN + bj + j4] = o;
    }
}

// ---- attention layer2 via MFMA. grid (256,4), 4 waves, wave covers disjoint j-subtile.
// partials indexed by jcw = jc*4+wv (16 total). pnum2T [16][32][4096].
__global__ __launch_bounds__(256) void k_attn2(
        const ushort_t* __restrict__ h2T,
        const float* __restrict__ ss2, const float* __restrict__ sd2,
        const uchar_t* __restrict__ abits,
        float* __restrict__ pnum2T, float* __restrict__ pden2){
    const int t = threadIdx.x;
    const int l = t & 63;
    const int wv = t >> 6;
    const int i0 = blockIdx.x*16;
    const int jc = blockIdx.y;
    const int lr = l & 15, lg = l >> 4;
    const int jcw = jc*4 + wv;

    f32x4 acc[2] = {};
    f32x4 dacc = {};
    const float ss = ss2[i0 + lr];
    bf16x8 ones;
    #pragma unroll
    for(int e=0;e<8;e++) ones[e] = (__bf16)1.0f;

    const uchar_t* arow = &abits[(size_t)(i0+lr)*512 + jc*128 + wv*4];

    for(int jt=0; jt<8; ++jt){
        const int jb = jc*1024 + jt*128 + wv*32 + lg*8;
        bf16x8 b[2];
        #pragma unroll
        for(int nt=0;nt<2;nt++)
            b[nt] = *(const bf16x8*)&h2T[(size_t)(nt*16 + lr)*NN + jb];
        uint_t bits = arow[jt*16 + lg];
        float4 sda = *(const float4*)&sd2[jb];
        float4 sdb = *(const float4*)&sd2[jb + 4];
        float sdv[8] = {sda.x,sda.y,sda.z,sda.w, sdb.x,sdb.y,sdb.z,sdb.w};
        bf16x8 a;
        #pragma unroll
        for(int e=0;e<8;e++){
            float s = ss + sdv[e];
            float tt = fmaxf(s, 0.2f*s);
            float w = EXP2(tt) * (float)((bits >> e) & 1u);
            a[e] = (__bf16)w;
        }
        #pragma unroll
        for(int nt=0;nt<2;nt++)
            acc[nt] = __builtin_amdgcn_mfma_f32_16x16x32_bf16(a, b[nt], acc[nt], 0, 0, 0);
        dacc = __builtin_amdgcn_mfma_f32_16x16x32_bf16(a, ones, dacc, 0, 0, 0);
    }
    #pragma unroll
    for(int nt=0;nt<2;nt++){
        int col = nt*16 + lr;
        float4 v = {acc[nt][0], acc[nt][1], acc[nt][2], acc[nt][3]};
        *(float4*)&pnum2T[((size_t)jcw*32 + col)*NN + i0 + lg*4] = v;
    }
    if (lr == 0){
        #pragma unroll
        for(int r=0;r<4;r++)
            pden2[(size_t)jcw*NN + i0 + lg*4 + r] = dacc[r];
    }
}

// ---- reduce layer2 -> final output
__global__ void k_reduce2(const float* __restrict__ pnum2T, const float* __restrict__ pden2,
                          float* __restrict__ out){
    int idx = blockIdx.x*256 + threadIdx.x;       // < 32*4096
    int c = idx >> 12, i = idx & 4095;
    float s = 0.f, d = 0.f;
    #pragma unroll
    for(int jcw=0;jcw<16;jcw++){
        s += pnum2T[((size_t)jcw*32 + c)*NN + i];
        d += pden2[(size_t)jcw*NN + i];
    }
    out[(size_t)i*32 + c] = elu1(s/d);
}

extern "C" void kernel_launch(void* const* d_in, const int* in_sizes, int n_in,
                              void* d_out, int out_size, void* d_ws, size_t ws_size,
                              hipStream_t stream){
    const float* x    = (const float*)d_in[0];
    const int*   adj  = (const int*)  d_in[1];
    const float* Watt = (const float*)d_in[2];
    const float* aatt = (const float*)d_in[3];
    const float* Wout = (const float*)d_in[4];
    const float* aout = (const float*)d_in[5];
    float* out = (float*)d_out;
    char* ws = (char*)d_ws;

    float*    h_all = (float*)   (ws + (size_t) 0*MB);  // 8 MB [4096][512]
    float*    hcatT = (float*)   (ws + (size_t) 0*MB);  // overlays (dead h_all) [512][4096]
    float*    W_all = (float*)   (ws + (size_t) 8*MB);  // 1 MB
    float*    ssrc2 = (float*)   (ws + (size_t) 9*MB);  // 128 KB [8][4096]
    float*    sdst2 = (float*)   (ws + (size_t)10*MB);  // 128 KB
    ushort_t* hT    = (ushort_t*)(ws + (size_t)11*MB);  // 4 MB [512][4096] bf16
    uint_t*   abits = (uint_t*)  (ws + (size_t)15*MB);  // 2 MB [4096][128]
    float*    h2    = (float*)   (ws + (size_t)17*MB);  // 512 KB [4096][32]
    float*    ss2   = (float*)   (ws + (size_t)18*MB);  // 16 KB
    float*    sd2   = (float*)   (ws + (size_t)19*MB);  // 16 KB
    ushort_t* h2T   = (ushort_t*)(ws + (size_t)20*MB);  // 256 KB [32][4096] bf16
    float*    pden  = (float*)   (ws + (size_t)21*MB);  // 512 KB [4][8][4096]
    float*    pnumT = (float*)   (ws + (size_t)22*MB);  // 32 MB [4][512][4096]
    float*    pnum2T= pnumT;                            // reused: [16][32][4096] 8MB
    float*    pden2 = (float*)   (ws + (size_t)21*MB) + 512*1024/4 + 0; // reuse tail? no:
    // pden2 [16][4096] = 256KB: place after pden's 512KB within 21MB..22MB window
    pden2 = (float*)(ws + (size_t)21*MB + 512*1024);
    if (ws_size < (size_t)55*MB) return;                // need 55 MB scratch

    k_repack  <<<1024, 256, 0, stream>>>(Watt, W_all);
    k_pack    <<<2048, 256, 0, stream>>>(adj, abits);
    k_gemm<64,4><<<dim3(64,8), 256, 0, stream>>>(x, W_all, h_all, NN, 512, 512);
    k_tr      <<<dim3(128,16), 256, 0, stream>>>(h_all, hT);
    k_scores1 <<<128, 256, 0, stream>>>(h_all, aatt, ssrc2, sdst2);
    k_attn1   <<<dim3(256,4), 256, 0, stream>>>(hT, ssrc2, sdst2, (const uchar_t*)abits, pnumT, pden);
    k_reduce1T<<<8192, 256, 0, stream>>>(pnumT, pden, hcatT);
    k_gemmAT  <<<128, 256, 0, stream>>>(hcatT, Wout, h2);
    k_scores2 <<<16, 256, 0, stream>>>(h2, aout, ss2, sd2);
    k_tr2     <<<64, 256, 0, stream>>>(h2, h2T);
    k_attn2   <<<dim3(256,4), 256, 0, stream>>>(h2T, ss2, sd2, (const uchar_t*)abits, pnum2T, pden2);
    k_reduce2 <<<512, 256, 0, stream>>>(pnum2T, pden2, out);
}

// Round 4
// 288.650 us; speedup vs baseline: 1.2023x; 1.2023x over previous
//
#include <hip/hip_runtime.h>
#include <math.h>

#define NN 4096      // nodes
#define CC 512       // concat dim = 8 heads * 64
#define MB (1024*1024)
#define LOG2E 1.4426950408889634f

typedef __attribute__((ext_vector_type(8))) __bf16 bf16x8;
typedef __attribute__((ext_vector_type(4))) float f32x4;
typedef unsigned short ushort_t;
typedef unsigned int uint_t;
typedef unsigned char uchar_t;

#if __has_builtin(__builtin_amdgcn_exp2f)
#define EXP2(x) __builtin_amdgcn_exp2f(x)
#else
#define EXP2(x) exp2f(x)
#endif

static __device__ __forceinline__ float elu1(float x){ return x > 0.f ? x : (__expf(x)-1.f); }
static __device__ __forceinline__ ushort_t f2bf(float f){
    union { float f; uint_t u; } v; v.f = f;
    uint_t r = (v.u + 0x7FFFu + ((v.u >> 16) & 1u)) >> 16;
    return (ushort_t)r;
}

// ---- repack W_att [8][512][64] -> W_all [512][512]  (W_all[k][hd*64+f])
__global__ void k_repack(const float* __restrict__ Watt, float* __restrict__ Wall){
    int idx = blockIdx.x*256 + threadIdx.x;            // < 512*512
    int k = idx >> 9, c = idx & 511;
    Wall[idx] = Watt[(c>>6)*(512*64) + k*64 + (c&63)];
}

// ---- pack adjacency to bits: abits[i][q] = bits of adj[i][q*32 .. +31]
__global__ void k_pack(const int* __restrict__ adj, uint_t* __restrict__ abits){
    int idx = blockIdx.x*256 + threadIdx.x;            // < 4096*128
    int i = idx >> 7, q = idx & 127;
    const int4* p = (const int4*)&adj[(size_t)i*NN + q*32];
    uint_t m = 0;
    #pragma unroll
    for(int g=0; g<8; g++){
        int4 v = p[g];
        m |= (uint_t)(v.x > 0) << (g*4 + 0);
        m |= (uint_t)(v.y > 0) << (g*4 + 1);
        m |= (uint_t)(v.z > 0) << (g*4 + 2);
        m |= (uint_t)(v.w > 0) << (g*4 + 3);
    }
    abits[idx] = m;
}

// ---- generic f32 GEMM: C[M,N]=A[M,K]@B[K,N], row-major. BM=64, BK=16, TM=4.
template<int BN, int TN>
__global__ __launch_bounds__(256) void k_gemm(const float* __restrict__ A,
                                              const float* __restrict__ B,
                                              float* __restrict__ C,
                                              int M, int N, int K){
    constexpr int BM = 64, BK = 16, TM = 4;
    __shared__ float As[BK][BM + 4];
    __shared__ float Bs[BK][BN];
    const int t = threadIdx.x;
    const int i0 = blockIdx.x*BM, j0 = blockIdx.y*BN;
    constexpr int nx = BN / TN;
    const int ty = t / nx, tx = t % nx;
    float acc[TM][TN];
    #pragma unroll
    for(int a=0;a<TM;a++){
        #pragma unroll
        for(int b=0;b<TN;b++) acc[a][b] = 0.f;
    }
    const int ai = t >> 2, ak = (t & 3)*4;
    for(int k0 = 0; k0 < K; k0 += BK){
        __syncthreads();
        float4 av = *(const float4*)&A[(size_t)(i0+ai)*K + k0 + ak];
        As[ak+0][ai]=av.x; As[ak+1][ai]=av.y; As[ak+2][ai]=av.z; As[ak+3][ai]=av.w;
        if constexpr (BN == 64){
            int bk = t >> 4, bj = (t & 15)*4;
            *(float4*)&Bs[bk][bj] = *(const float4*)&B[(size_t)(k0+bk)*N + j0 + bj];
        } else {
            if (t < 128){
                int bk = t >> 3, bj = (t & 7)*4;
                *(float4*)&Bs[bk][bj] = *(const float4*)&B[(size_t)(k0+bk)*N + j0 + bj];
            }
        }
        __syncthreads();
        #pragma unroll
        for(int k=0;k<BK;k++){
            float4 a4 = *(const float4*)&As[k][ty*TM];
            float ar[4] = {a4.x, a4.y, a4.z, a4.w};
            if constexpr (TN == 4){
                float4 b4 = *(const float4*)&Bs[k][tx*4];
                float br[4] = {b4.x, b4.y, b4.z, b4.w};
                #pragma unroll
                for(int a=0;a<TM;a++){
                    #pragma unroll
                    for(int b=0;b<4;b++) acc[a][b] += ar[a]*br[b];
                }
            } else {
                float2 b2 = *(const float2*)&Bs[k][tx*2];
                #pragma unroll
                for(int a=0;a<TM;a++){ acc[a][0] += ar[a]*b2.x; acc[a][1] += ar[a]*b2.y; }
            }
        }
    }
    #pragma unroll
    for(int a=0;a<TM;a++){
        float* cp = &C[(size_t)(i0 + ty*TM + a)*N + j0 + tx*TN];
        if constexpr (TN == 4){
            float4 v = {acc[a][0], acc[a][1], acc[a][2], acc[a][3]};
            *(float4*)cp = v;
        } else {
            float2 v = {acc[a][0], acc[a][1]};
            *(float2*)cp = v;
        }
    }
}

// ---- transpose h_all [4096][512] f32 -> hT [512][4096] bf16 bits
__global__ __launch_bounds__(256) void k_tr(const float* __restrict__ h, ushort_t* __restrict__ hT){
    __shared__ float tile[32][33];
    const int bj = blockIdx.x*32, bc = blockIdx.y*32;
    const int tx = threadIdx.x & 31, ty = threadIdx.x >> 5;   // 32 x 8
    #pragma unroll
    for(int r=0;r<4;r++)
        tile[ty + r*8][tx] = h[(size_t)(bj + ty + r*8)*512 + bc + tx];
    __syncthreads();
    #pragma unroll
    for(int r=0;r<4;r++)
        hT[(size_t)(bc + ty + r*8)*NN + bj + tx] = f2bf(tile[tx][ty + r*8]);
}

// ---- scores layer1 (pre-scaled by log2e)
__global__ void k_scores1(const float* __restrict__ hall, const float* __restrict__ aatt,
                          float* __restrict__ ssrc2, float* __restrict__ sdst2){
    int t = threadIdx.x;
    int hd = t & 7, il = t >> 3;
    int i = blockIdx.x*32 + il;
    const float4* h4 = (const float4*)&hall[(size_t)i*CC + hd*64];
    const float4* a1 = (const float4*)&aatt[hd*128];
    const float4* a2 = (const float4*)&aatt[hd*128 + 64];
    float ss = 0.f, sd = 0.f;
    #pragma unroll
    for(int q=0;q<16;q++){
        float4 h = h4[q], u = a1[q], v = a2[q];
        ss += h.x*u.x + h.y*u.y + h.z*u.z + h.w*u.w;
        sd += h.x*v.x + h.y*v.y + h.z*v.z + h.w*v.w;
    }
    ssrc2[hd*NN + i] = ss*LOG2E;
    sdst2[hd*NN + i] = sd*LOG2E;
}

// ---- attention layer1 via MFMA, 2-deep software pipeline.
// grid (128, 4), block 256 = 4 waves; wave = heads {2w,2w+1}, i-tile 32 (mh=2).
// j-chunk 1024 (32 K-tiles of 32). pnumT layout [jc][col 512][i 4096].
__global__ __launch_bounds__(256) void k_attn1(
        const ushort_t* __restrict__ hT,
        const float* __restrict__ ssrc2, const float* __restrict__ sdst2,
        const uchar_t* __restrict__ abits,
        float* __restrict__ pnumT, float* __restrict__ pden){
    const int t = threadIdx.x;
    const int l = t & 63;
    const int hd0 = (t >> 6)*2;
    const int i0 = blockIdx.x*32;
    const int jc = blockIdx.y;
    const int lr = l & 15;     // A row / B col / C col
    const int lg = l >> 4;     // k-group (8 j's) / C row-group

    f32x4 acc[2][2][4] = {};   // [hd][mh][nt]
    f32x4 dacc[2][2] = {};     // denominators via ones-MFMA

    float ss[2][2];
    #pragma unroll
    for(int hd=0;hd<2;hd++)
        #pragma unroll
        for(int mh=0;mh<2;mh++)
            ss[hd][mh] = ssrc2[(hd0+hd)*NN + i0 + mh*16 + lr];

    bf16x8 ones;
    #pragma unroll
    for(int e=0;e<8;e++) ones[e] = (__bf16)1.0f;

    const uchar_t* arow0 = &abits[(size_t)(i0 + lr)*512 + jc*128];
    const uchar_t* arow1 = &abits[(size_t)(i0 + 16 + lr)*512 + jc*128];

    // pipeline buffers (named, static indexing only)
    bf16x8 bA[2][4], bB[2][4];
    float4 sdaA[2], sdbA[2], sdaB[2], sdbB[2];
    uint_t bitsA0, bitsA1, bitsB0, bitsB1;

#define LOAD1(SFX, JT) { \
    const int jb_ = jc*1024 + (JT)*32 + lg*8; \
    _Pragma("unroll") \
    for(int hd=0;hd<2;hd++){ \
        _Pragma("unroll") \
        for(int nt=0;nt<4;nt++) \
            b##SFX[hd][nt] = *(const bf16x8*)&hT[(size_t)((hd0+hd)*64 + nt*16 + lr)*NN + jb_]; \
        sda##SFX[hd] = *(const float4*)&sdst2[(hd0+hd)*NN + jb_]; \
        sdb##SFX[hd] = *(const float4*)&sdst2[(hd0+hd)*NN + jb_ + 4]; \
    } \
    bits##SFX##0 = arow0[(JT)*4 + lg]; \
    bits##SFX##1 = arow1[(JT)*4 + lg]; }

#define COMP1(SFX) { \
    _Pragma("unroll") \
    for(int hd=0;hd<2;hd++){ \
        float sdv[8] = {sda##SFX[hd].x, sda##SFX[hd].y, sda##SFX[hd].z, sda##SFX[hd].w, \
                        sdb##SFX[hd].x, sdb##SFX[hd].y, sdb##SFX[hd].z, sdb##SFX[hd].w}; \
        _Pragma("unroll") \
        for(int mh=0;mh<2;mh++){ \
            const uint_t bits = mh ? bits##SFX##1 : bits##SFX##0; \
            bf16x8 a; \
            _Pragma("unroll") \
            for(int e=0;e<8;e++){ \
                float s_ = ss[hd][mh] + sdv[e]; \
                float t_ = fmaxf(s_, 0.2f*s_); \
                float w_ = EXP2(t_) * (float)((bits >> e) & 1u); \
                a[e] = (__bf16)w_; \
            } \
            _Pragma("unroll") \
            for(int nt=0;nt<4;nt++) \
                acc[hd][mh][nt] = __builtin_amdgcn_mfma_f32_16x16x32_bf16( \
                    a, b##SFX[hd][nt], acc[hd][mh][nt], 0, 0, 0); \
            dacc[hd][mh] = __builtin_amdgcn_mfma_f32_16x16x32_bf16( \
                    a, ones, dacc[hd][mh], 0, 0, 0); \
        } \
    } }

    LOAD1(A, 0);
    for(int jt=0; jt<32; jt+=2){
        LOAD1(B, jt+1);
        COMP1(A);
        if (jt + 2 < 32) LOAD1(A, jt+2);
        COMP1(B);
    }
#undef LOAD1
#undef COMP1

    // write pnumT: col = hd*64+nt*16+lr, rows i0+mh*16+lg*4 .. +3 -> float4
    #pragma unroll
    for(int hd=0;hd<2;hd++)
        #pragma unroll
        for(int mh=0;mh<2;mh++)
            #pragma unroll
            for(int nt=0;nt<4;nt++){
                int col = (hd0+hd)*64 + nt*16 + lr;
                float4 v = {acc[hd][mh][nt][0], acc[hd][mh][nt][1],
                            acc[hd][mh][nt][2], acc[hd][mh][nt][3]};
                *(float4*)&pnumT[((size_t)jc*512 + col)*NN + i0 + mh*16 + lg*4] = v;
            }
    if (lr == 0){
        #pragma unroll
        for(int hd=0;hd<2;hd++)
            #pragma unroll
            for(int mh=0;mh<2;mh++)
                #pragma unroll
                for(int r=0;r<4;r++)
                    pden[((size_t)jc*8 + hd0+hd)*NN + i0 + mh*16 + lg*4 + r] = dacc[hd][mh][r];
    }
}

// ---- reduce layer1: hcatT[c][i] = elu( sum_jc pnumT / sum_jc pden )
__global__ void k_reduce1T(const float* __restrict__ pnumT, const float* __restrict__ pden,
                           float* __restrict__ hcatT){
    int idx = blockIdx.x*256 + threadIdx.x;           // < 512*4096
    int c = idx >> 12, i = idx & 4095, hd = c >> 6;
    float s = 0.f, d = 0.f;
    #pragma unroll
    for(int jc=0;jc<4;jc++){
        s += pnumT[((size_t)jc*512 + c)*NN + i];
        d += pden[((size_t)jc*8 + hd)*NN + i];
    }
    hcatT[(size_t)c*NN + i] = elu1(s/d);
}

// ---- gemm2 from transposed A: C[4096][32] = AT[512][4096]^T @ B[512][32]
__global__ __launch_bounds__(256) void k_gemmAT(const float* __restrict__ AT,
                                                const float* __restrict__ B,
                                                float* __restrict__ C){
    __shared__ float As[32][32];   // [k][i]
    __shared__ float Bs[32][32];   // [k][n]
    const int t = threadIdx.x;
    const int i0 = blockIdx.x*32;
    const int ty = t >> 4, tx = t & 15;
    float acc[2][2] = {{0.f,0.f},{0.f,0.f}};
    for(int k0=0;k0<512;k0+=32){
        __syncthreads();
        { int k = t >> 3, i4 = (t & 7)*4;
          *(float4*)&As[k][i4] = *(const float4*)&AT[(size_t)(k0+k)*NN + i0 + i4]; }
        { int k = t >> 3, n4 = (t & 7)*4;
          *(float4*)&Bs[k][n4] = *(const float4*)&B[(size_t)(k0+k)*32 + n4]; }
        __syncthreads();
        #pragma unroll
        for(int k=0;k<32;k++){
            float2 a2 = *(const float2*)&As[k][ty*2];
            float2 b2 = *(const float2*)&Bs[k][tx*2];
            acc[0][0] += a2.x*b2.x; acc[0][1] += a2.x*b2.y;
            acc[1][0] += a2.y*b2.x; acc[1][1] += a2.y*b2.y;
        }
    }
    #pragma unroll
    for(int a=0;a<2;a++){
        float2 v = {acc[a][0], acc[a][1]};
        *(float2*)&C[(size_t)(i0 + ty*2 + a)*32 + tx*2] = v;
    }
}

// ---- scores layer2 (pre-scaled by log2e)
__global__ void k_scores2(const float* __restrict__ h2, const float* __restrict__ aout,
                          float* __restrict__ ss2, float* __restrict__ sd2){
    int i = blockIdx.x*256 + threadIdx.x;
    const float4* h4 = (const float4*)&h2[(size_t)i*32];
    const float4* a1 = (const float4*)aout;
    const float4* a2 = (const float4*)&aout[32];
    float ss = 0.f, sd = 0.f;
    #pragma unroll
    for(int q=0;q<8;q++){
        float4 h = h4[q], u = a1[q], v = a2[q];
        ss += h.x*u.x + h.y*u.y + h.z*u.z + h.w*u.w;
        sd += h.x*v.x + h.y*v.y + h.z*v.z + h.w*v.w;
    }
    ss2[i] = ss*LOG2E; sd2[i] = sd*LOG2E;
}

// ---- transpose h2 [4096][32] f32 -> h2T [32][4096] bf16
__global__ __launch_bounds__(256) void k_tr2(const float* __restrict__ h2, ushort_t* __restrict__ h2T){
    __shared__ float tile[64][33];
    const int bj = blockIdx.x*64;
    const int t = threadIdx.x;
    const int tx = t & 31, ty = t >> 5;
    #pragma unroll
    for(int r=0;r<8;r++)
        tile[ty + r*8][tx] = h2[(size_t)(bj + ty + r*8)*32 + tx];
    __syncthreads();
    #pragma unroll
    for(int half=0; half<2; half++){
        int c = (t >> 4) + half*16;
        int j4 = (t & 15)*4;
        ushort4 o;
        o.x = f2bf(tile[j4+0][c]); o.y = f2bf(tile[j4+1][c]);
        o.z = f2bf(tile[j4+2][c]); o.w = f2bf(tile[j4+3][c]);
        *(ushort4*)&h2T[(size_t)c*NN + bj + j4] = o;
    }
}

// ---- attention layer2 via MFMA, 2-deep pipeline. grid (256,4), 4 waves,
// wave covers disjoint j-subtile. jcw = jc*4+wv (16 partials). pnum2T [16][32][4096].
__global__ __launch_bounds__(256) void k_attn2(
        const ushort_t* __restrict__ h2T,
        const float* __restrict__ ss2, const float* __restrict__ sd2,
        const uchar_t* __restrict__ abits,
        float* __restrict__ pnum2T, float* __restrict__ pden2){
    const int t = threadIdx.x;
    const int l = t & 63;
    const int wv = t >> 6;
    const int i0 = blockIdx.x*16;
    const int jc = blockIdx.y;
    const int lr = l & 15, lg = l >> 4;
    const int jcw = jc*4 + wv;

    f32x4 acc[2] = {};
    f32x4 dacc = {};
    const float ss = ss2[i0 + lr];
    bf16x8 ones;
    #pragma unroll
    for(int e=0;e<8;e++) ones[e] = (__bf16)1.0f;

    const uchar_t* arow = &abits[(size_t)(i0+lr)*512 + jc*128 + wv*4];

    bf16x8 bA[2], bB[2];
    float4 sdaA, sdbA, sdaB, sdbB;
    uint_t bitsA, bitsB;

#define LOAD2(SFX, JT) { \
    const int jb_ = jc*1024 + (JT)*128 + wv*32 + lg*8; \
    _Pragma("unroll") \
    for(int nt=0;nt<2;nt++) \
        b##SFX[nt] = *(const bf16x8*)&h2T[(size_t)(nt*16 + lr)*NN + jb_]; \
    sda##SFX = *(const float4*)&sd2[jb_]; \
    sdb##SFX = *(const float4*)&sd2[jb_ + 4]; \
    bits##SFX = arow[(JT)*16 + lg]; }

#define COMP2(SFX) { \
    float sdv[8] = {sda##SFX.x, sda##SFX.y, sda##SFX.z, sda##SFX.w, \
                    sdb##SFX.x, sdb##SFX.y, sdb##SFX.z, sdb##SFX.w}; \
    bf16x8 a; \
    _Pragma("unroll") \
    for(int e=0;e<8;e++){ \
        float s_ = ss + sdv[e]; \
        float t_ = fmaxf(s_, 0.2f*s_); \
        float w_ = EXP2(t_) * (float)((bits##SFX >> e) & 1u); \
        a[e] = (__bf16)w_; \
    } \
    _Pragma("unroll") \
    for(int nt=0;nt<2;nt++) \
        acc[nt] = __builtin_amdgcn_mfma_f32_16x16x32_bf16(a, b##SFX[nt], acc[nt], 0, 0, 0); \
    dacc = __builtin_amdgcn_mfma_f32_16x16x32_bf16(a, ones, dacc, 0, 0, 0); }

    LOAD2(A, 0);
    for(int jt=0; jt<8; jt+=2){
        LOAD2(B, jt+1);
        COMP2(A);
        if (jt + 2 < 8) LOAD2(A, jt+2);
        COMP2(B);
    }
#undef LOAD2
#undef COMP2

    #pragma unroll
    for(int nt=0;nt<2;nt++){
        int col = nt*16 + lr;
        float4 v = {acc[nt][0], acc[nt][1], acc[nt][2], acc[nt][3]};
        *(float4*)&pnum2T[((size_t)jcw*32 + col)*NN + i0 + lg*4] = v;
    }
    if (lr == 0){
        #pragma unroll
        for(int r=0;r<4;r++)
            pden2[(size_t)jcw*NN + i0 + lg*4 + r] = dacc[r];
    }
}

// ---- reduce layer2 -> final output
__global__ void k_reduce2(const float* __restrict__ pnum2T, const float* __restrict__ pden2,
                          float* __restrict__ out){
    int idx = blockIdx.x*256 + threadIdx.x;       // < 32*4096
    int c = idx >> 12, i = idx & 4095;
    float s = 0.f, d = 0.f;
    #pragma unroll
    for(int jcw=0;jcw<16;jcw++){
        s += pnum2T[((size_t)jcw*32 + c)*NN + i];
        d += pden2[(size_t)jcw*NN + i];
    }
    out[(size_t)i*32 + c] = elu1(s/d);
}

extern "C" void kernel_launch(void* const* d_in, const int* in_sizes, int n_in,
                              void* d_out, int out_size, void* d_ws, size_t ws_size,
                              hipStream_t stream){
    const float* x    = (const float*)d_in[0];
    const int*   adj  = (const int*)  d_in[1];
    const float* Watt = (const float*)d_in[2];
    const float* aatt = (const float*)d_in[3];
    const float* Wout = (const float*)d_in[4];
    const float* aout = (const float*)d_in[5];
    float* out = (float*)d_out;
    char* ws = (char*)d_ws;

    float*    h_all = (float*)   (ws + (size_t) 0*MB);  // 8 MB [4096][512]
    float*    hcatT = (float*)   (ws + (size_t) 0*MB);  // overlays dead h_all [512][4096]
    float*    W_all = (float*)   (ws + (size_t) 8*MB);  // 1 MB
    float*    ssrc2 = (float*)   (ws + (size_t) 9*MB);  // 128 KB [8][4096]
    float*    sdst2 = (float*)   (ws + (size_t)10*MB);  // 128 KB
    ushort_t* hT    = (ushort_t*)(ws + (size_t)11*MB);  // 4 MB [512][4096] bf16
    uint_t*   abits = (uint_t*)  (ws + (size_t)15*MB);  // 2 MB [4096][128]
    float*    h2    = (float*)   (ws + (size_t)17*MB);  // 512 KB [4096][32]
    float*    ss2   = (float*)   (ws + (size_t)18*MB);  // 16 KB
    float*    sd2   = (float*)   (ws + (size_t)19*MB);  // 16 KB
    ushort_t* h2T   = (ushort_t*)(ws + (size_t)20*MB);  // 256 KB [32][4096] bf16
    float*    pden  = (float*)   (ws + (size_t)21*MB);  // 512 KB [4][8][4096]
    float*    pden2 = (float*)   (ws + (size_t)21*MB + 512*1024); // 256 KB [16][4096]
    float*    pnumT = (float*)   (ws + (size_t)22*MB);  // 32 MB [4][512][4096]
    float*    pnum2T= pnumT;                            // reused: [16][32][4096] 8MB
    if (ws_size < (size_t)55*MB) return;                // need 55 MB scratch

    k_repack  <<<1024, 256, 0, stream>>>(Watt, W_all);
    k_pack    <<<2048, 256, 0, stream>>>(adj, abits);
    k_gemm<64,4><<<dim3(64,8), 256, 0, stream>>>(x, W_all, h_all, NN, 512, 512);
    k_tr      <<<dim3(128,16), 256, 0, stream>>>(h_all, hT);
    k_scores1 <<<128, 256, 0, stream>>>(h_all, aatt, ssrc2, sdst2);
    k_attn1   <<<dim3(128,4), 256, 0, stream>>>(hT, ssrc2, sdst2, (const uchar_t*)abits, pnumT, pden);
    k_reduce1T<<<8192, 256, 0, stream>>>(pnumT, pden, hcatT);
    k_gemmAT  <<<128, 256, 0, stream>>>(hcatT, Wout, h2);
    k_scores2 <<<16, 256, 0, stream>>>(h2, aout, ss2, sd2);
    k_tr2     <<<64, 256, 0, stream>>>(h2, h2T);
    k_attn2   <<<dim3(256,4), 256, 0, stream>>>(h2T, ss2, sd2, (const uchar_t*)abits, pnum2T, pden2);
    k_reduce2 <<<512, 256, 0, stream>>>(pnum2T, pden2, out);
}